// Round 3
// baseline (422.224 us; speedup 1.0000x reference)
//
#include <hip/hip_runtime.h>

// BackprojectDepth: out[b, 0:3, n] = depth[b, n] * (invK[b,0:3,0:3] @ [x, y, 1]),
//                   out[b, 3, n]   = 1.0
// where x = n % W + dxy[b,0], y = n / W + dxy[b,1].
// B=32, H=512, W=1024. Pure streaming: 64 MB read + 256 MB write.
// R3: same as R2 but with Clang ext_vector_type for the nontemporal builtins
//     (HIP float4 is a struct — rejected by __builtin_nontemporal_*).

#define BB 32
#define HH 512
#define WW 1024
#define HWN (HH * WW)   // 524288
#define PXT 8           // pixels per thread

typedef float vf4 __attribute__((ext_vector_type(4)));  // native vector, nt-capable

__global__ __launch_bounds__(256) void backproject_kernel(
    const float* __restrict__ depth,   // [B, 1, H, W]
    const float* __restrict__ invK,    // [B, 4, 4]
    const int*   __restrict__ dxy,     // [B, 2]
    float*       __restrict__ out)     // [B, 4, H*W]
{
    const int b  = blockIdx.y;                                 // wave-uniform
    const int n0 = (blockIdx.x * 256 + threadIdx.x) * PXT;     // first pixel

    // Uniform (scalar) loads
    const float k00 = invK[b * 16 + 0];
    const float k01 = invK[b * 16 + 1];
    const float k02 = invK[b * 16 + 2];
    const float k10 = invK[b * 16 + 4];
    const float k11 = invK[b * 16 + 5];
    const float k12 = invK[b * 16 + 6];
    const float k20 = invK[b * 16 + 8];
    const float k21 = invK[b * 16 + 9];
    const float k22 = invK[b * 16 + 10];
    const float dx  = (float)dxy[b * 2 + 0];
    const float dy  = (float)dxy[b * 2 + 1];

    // y constant across the 8-px run (W=1024 multiple of 8, n0 8-aligned)
    const float y  = (float)(n0 >> 10) + dy;        // n0 / W
    const float x0 = (float)(n0 & (WW - 1)) + dx;   // n0 % W

    const float c0 = k01 * y + k02;
    const float c1 = k11 * y + k12;
    const float c2 = k21 * y + k22;

    const vf4* dp = (const vf4*)(depth + (size_t)b * HWN + n0);
    const vf4 da = __builtin_nontemporal_load(dp + 0);
    const vf4 db = __builtin_nontemporal_load(dp + 1);

    float* outb = out + (size_t)b * 4 * HWN;
    const vf4 ones = {1.f, 1.f, 1.f, 1.f};

    #pragma unroll
    for (int h = 0; h < 2; ++h) {                 // two float4 groups
        const vf4  d  = h ? db : da;
        const float xb = x0 + 4.f * h;
        vf4 r0, r1, r2;
        r0.x = d.x * (k00 * (xb + 0.f) + c0);
        r0.y = d.y * (k00 * (xb + 1.f) + c0);
        r0.z = d.z * (k00 * (xb + 2.f) + c0);
        r0.w = d.w * (k00 * (xb + 3.f) + c0);

        r1.x = d.x * (k10 * (xb + 0.f) + c1);
        r1.y = d.y * (k10 * (xb + 1.f) + c1);
        r1.z = d.z * (k10 * (xb + 2.f) + c1);
        r1.w = d.w * (k10 * (xb + 3.f) + c1);

        r2.x = d.x * (k20 * (xb + 0.f) + c2);
        r2.y = d.y * (k20 * (xb + 1.f) + c2);
        r2.z = d.z * (k20 * (xb + 2.f) + c2);
        r2.w = d.w * (k20 * (xb + 3.f) + c2);

        const int n = n0 + 4 * h;
        __builtin_nontemporal_store(r0,   (vf4*)(outb + 0 * HWN + n));
        __builtin_nontemporal_store(r1,   (vf4*)(outb + 1 * HWN + n));
        __builtin_nontemporal_store(r2,   (vf4*)(outb + 2 * HWN + n));
        __builtin_nontemporal_store(ones, (vf4*)(outb + 3 * HWN + n));
    }
}

extern "C" void kernel_launch(void* const* d_in, const int* in_sizes, int n_in,
                              void* d_out, int out_size, void* d_ws, size_t ws_size,
                              hipStream_t stream) {
    const float* depth = (const float*)d_in[0];
    const float* invK  = (const float*)d_in[1];
    const int*   dxy   = (const int*)d_in[2];
    float*       out   = (float*)d_out;

    dim3 grid(HWN / (256 * PXT), BB);   // 256 x 32 blocks
    backproject_kernel<<<grid, 256, 0, stream>>>(depth, invK, dxy, out);
}

// Round 4
// 310.492 us; speedup vs baseline: 1.3599x; 1.3599x over previous
//
#include <hip/hip_runtime.h>

// BackprojectDepth: out[b, 0:3, n] = depth[b, n] * (invK[b,0:3,0:3] @ [x, y, 1]),
//                   out[b, 3, n]   = 1.0
// where x = n % W + dxy[b,0], y = n / W + dxy[b,1].
// B=32, H=512, W=1024. Pure streaming: 64 MB read + 256 MB write.
//
// R4: fix R3's 2x write amplification (WRITE_SIZE 506 MB vs 256 MB output).
// R3's PXT=8 put each thread's two float4s adjacent (n0, n0+4) -> one store
// instruction spanned 64 lanes x 16B at 32B stride: every line half-written
// per instruction; nt early-evict flushed each half separately. Now each
// block owns TWO FULL ROWS (W = 256 threads * 4 px): float4 #1 at row r,
// float4 #2 at row r+1, same x. Every store instruction is a contiguous
// aligned 4 KB wave-segment. nt stores only on output (256 MB >> 32 MB L2);
// plain cached loads for depth (L3-resident, FETCH showed 33 MB < 64 MB).

#define BB 32
#define HH 512
#define WW 1024
#define HWN (HH * WW)   // 524288

typedef float vf4 __attribute__((ext_vector_type(4)));  // native vector, nt-capable

__global__ __launch_bounds__(256) void backproject_kernel(
    const float* __restrict__ depth,   // [B, 1, H, W]
    const float* __restrict__ invK,    // [B, 4, 4]
    const int*   __restrict__ dxy,     // [B, 2]
    float*       __restrict__ out)     // [B, 4, H*W]
{
    const int tid  = threadIdx.x;
    const int b    = blockIdx.y;                 // wave-uniform
    const int row0 = blockIdx.x * 2;             // block covers rows row0, row0+1
    const int xpix = tid * 4;                    // x pixel of this thread's quad
    const int n0   = row0 * WW + xpix;           // pixel index, row 0 of pair

    // Uniform (scalar) loads
    const float k00 = invK[b * 16 + 0];
    const float k01 = invK[b * 16 + 1];
    const float k02 = invK[b * 16 + 2];
    const float k10 = invK[b * 16 + 4];
    const float k11 = invK[b * 16 + 5];
    const float k12 = invK[b * 16 + 6];
    const float k20 = invK[b * 16 + 8];
    const float k21 = invK[b * 16 + 9];
    const float k22 = invK[b * 16 + 10];
    const float dx  = (float)dxy[b * 2 + 0];
    const float dy  = (float)dxy[b * 2 + 1];

    const float x0 = (float)xpix + dx;           // same x for both rows

    // Cached (L3-served) depth loads, one per row — each contiguous per wave
    const float* dbase = depth + (size_t)b * HWN + n0;
    const vf4 da = *(const vf4*)(dbase);
    const vf4 db = *(const vf4*)(dbase + WW);

    float* outb = out + (size_t)b * 4 * HWN;
    const vf4 ones = {1.f, 1.f, 1.f, 1.f};

    #pragma unroll
    for (int h = 0; h < 2; ++h) {                // two rows
        const vf4   d = h ? db : da;
        const float y = (float)(row0 + h) + dy;
        const float c0 = k01 * y + k02;
        const float c1 = k11 * y + k12;
        const float c2 = k21 * y + k22;

        vf4 r0, r1, r2;
        r0.x = d.x * (k00 * (x0 + 0.f) + c0);
        r0.y = d.y * (k00 * (x0 + 1.f) + c0);
        r0.z = d.z * (k00 * (x0 + 2.f) + c0);
        r0.w = d.w * (k00 * (x0 + 3.f) + c0);

        r1.x = d.x * (k10 * (x0 + 0.f) + c1);
        r1.y = d.y * (k10 * (x0 + 1.f) + c1);
        r1.z = d.z * (k10 * (x0 + 2.f) + c1);
        r1.w = d.w * (k10 * (x0 + 3.f) + c1);

        r2.x = d.x * (k20 * (x0 + 0.f) + c2);
        r2.y = d.y * (k20 * (x0 + 1.f) + c2);
        r2.z = d.z * (k20 * (x0 + 2.f) + c2);
        r2.w = d.w * (k20 * (x0 + 3.f) + c2);

        const int n = n0 + h * WW;
        __builtin_nontemporal_store(r0,   (vf4*)(outb + 0 * HWN + n));
        __builtin_nontemporal_store(r1,   (vf4*)(outb + 1 * HWN + n));
        __builtin_nontemporal_store(r2,   (vf4*)(outb + 2 * HWN + n));
        __builtin_nontemporal_store(ones, (vf4*)(outb + 3 * HWN + n));
    }
}

extern "C" void kernel_launch(void* const* d_in, const int* in_sizes, int n_in,
                              void* d_out, int out_size, void* d_ws, size_t ws_size,
                              hipStream_t stream) {
    const float* depth = (const float*)d_in[0];
    const float* invK  = (const float*)d_in[1];
    const int*   dxy   = (const int*)d_in[2];
    float*       out   = (float*)d_out;

    dim3 grid(HH / 2, BB);   // 256 x 32 blocks, each does 2 rows of one batch
    backproject_kernel<<<grid, 256, 0, stream>>>(depth, invK, dxy, out);
}